// Round 15
// baseline (205.830 us; speedup 1.0000x reference)
//
#include <hip/hip_runtime.h>
#include <math.h>

#define N_NODES 100000
#define N_EDGES 3200000
#define F_IN    37
#define H_DIM   16
#define C_DIM   2

#define BUCKET_BITS 7
#define BUCKET_SZ   128
#define NBUCK       782          // ceil(100000/128)
#define CAP         4736         // bucket capacity: mean 4096 + 10 sigma (even!)
#define NPBLK       256          // k_part grid: one block per CU
#define EB          12500        // edges per part block (256*12500 = 3.2M exactly)
#define NV          3125         // int4 vectors per part block (EB/4)

__device__ __forceinline__ unsigned bf16rne(float f) {
    unsigned u = __float_as_uint(f);
    return (u + 0x7FFFu + ((u >> 16) & 1u)) >> 16;
}
#define BLO(u) __uint_as_float((u) << 16)
#define BHI(u) __uint_as_float((u) & 0xFFFF0000u)
// compact edge decode: u = (w_bf16 << 17) | row   (w in [0,1) => sign bit 0)
#define EW(u)  __uint_as_float(((u) >> 17) << 16)
#define ER(u)  ((u) & 0x1FFFFu)

// ---------- partition edges into destination buckets ----------
// grid = 256 (all CUs busy; R13's 196-block grid idled 60 CUs).
// packed: (row | col_local<<17, w_fp32); scattered ebuf writes are REGULAR
// stores (L2 merges ~16-edge runs; NT here was the R11 103MB regression).
__global__ __launch_bounds__(1024) void k_part(
    const int* __restrict__ row, const int* __restrict__ col,
    const float* __restrict__ w, int* __restrict__ gcur, int2* __restrict__ ebuf)
{
    __shared__ int cnt[NBUCK];
    __shared__ int gbase[NBUCK];
    int t = threadIdx.x;
    size_t e0 = (size_t)blockIdx.x * EB;
    const int4*   r4 = (const int4*)(row + e0);
    const int4*   c4 = (const int4*)(col + e0);
    const float4* w4 = (const float4*)(w + e0);

    int bk[4][4], rc[4][4], lofs[4][4];
    float wv[4][4];

    if (t < NBUCK) cnt[t] = 0;
    __syncthreads();
#pragma unroll
    for (int k = 0; k < 4; k++) {
        int idx = k * 1024 + t;
        if (idx < NV) {
            int4   rr = r4[idx];
            int4   cc = c4[idx];
            float4 ww = w4[idx];
            int rs[4] = {rr.x, rr.y, rr.z, rr.w};
            int cs[4] = {cc.x, cc.y, cc.z, cc.w};
            float wss[4] = {ww.x, ww.y, ww.z, ww.w};
#pragma unroll
            for (int j = 0; j < 4; j++) {
                int c = cs[j];
                bk[k][j] = c >> BUCKET_BITS;
                rc[k][j] = rs[j] | ((c & (BUCKET_SZ - 1)) << 17);
                wv[k][j] = wss[j];
                lofs[k][j] = atomicAdd(&cnt[bk[k][j]], 1);
            }
        } else {
#pragma unroll
            for (int j = 0; j < 4; j++) bk[k][j] = -1;
        }
    }
    __syncthreads();
    if (t < NBUCK) gbase[t] = t * CAP + atomicAdd(&gcur[t], cnt[t]);
    __syncthreads();
#pragma unroll
    for (int k = 0; k < 4; k++)
#pragma unroll
        for (int j = 0; j < 4; j++)
            if (bk[k][j] >= 0)
                ebuf[gbase[bk[k][j]] + lofs[k][j]] =
                    make_int2(rc[k][j], __float_as_int(wv[k][j]));
}

// ---------- fused: per-bucket LDS counting sort -> compact 4B edges + CSR
//            + dinv + h1b = bf16(dinv * (x @ W1)) for this bucket's nodes ----------
__global__ __launch_bounds__(1024) void k_sortxw1(
    const int* __restrict__ gcur, const int2* __restrict__ ebuf,
    const float* __restrict__ x, const float* __restrict__ W1,
    unsigned* __restrict__ ebuf4, int2* __restrict__ rp,
    float* __restrict__ dinv, unsigned* __restrict__ h1b)
{
    __shared__ int2  stage[CAP];              // 37.9 KB (reused as xs below)
    __shared__ int   cnt[BUCKET_SZ];
    __shared__ int   base[BUCKET_SZ];
    __shared__ float sdinv[BUCKET_SZ];
    __shared__ float sW[F_IN * H_DIM];        // 2.4 KB
    float* xs = (float*)stage;                // aliased reuse: 128*37 floats

    int t = threadIdx.x, b = blockIdx.x;
    int s = b * CAP;                          // even -> 16B-aligned pairs
    int len = gcur[b];                        // per-bucket count (memset base 0)
    int nbase = b << BUCKET_BITS;
    if (t < BUCKET_SZ) cnt[t] = 0;
    __syncthreads();

    // ---- load (int4 = 2 edges/inst) + count ----
    int npair = (len + 1) >> 1;
    int4 pv[3]; int cl[3][2], lofs[3][2];
#pragma unroll
    for (int k = 0; k < 3; k++) {
        int pi = k * 1024 + t;
        cl[k][0] = cl[k][1] = -1;
        if (pi < npair) {
            int4 v = ((const int4*)(ebuf + s))[pi];
            pv[k] = v;
            cl[k][0] = v.x >> 17;
            lofs[k][0] = atomicAdd(&cnt[cl[k][0]], 1);
            if (2 * pi + 1 < len) {
                cl[k][1] = v.z >> 17;
                lofs[k][1] = atomicAdd(&cnt[cl[k][1]], 1);
            }
        }
    }
    __syncthreads();
    // ---- inclusive scan of cnt[128] ----
    if (t < BUCKET_SZ) base[t] = cnt[t];
    __syncthreads();
    for (int off = 1; off < BUCKET_SZ; off <<= 1) {
        int v2 = 0;
        if (t < BUCKET_SZ && t >= off) v2 = base[t - off];
        __syncthreads();
        if (t < BUCKET_SZ) base[t] += v2;
        __syncthreads();
    }
    // ---- scatter into LDS stage in node-sorted order ----
#pragma unroll
    for (int k = 0; k < 3; k++) {
        if (cl[k][0] >= 0) {
            int pos = base[cl[k][0]] - cnt[cl[k][0]] + lofs[k][0];
            stage[pos] = make_int2(pv[k].x, pv[k].y);
        }
        if (cl[k][1] >= 0) {
            int pos = base[cl[k][1]] - cnt[cl[k][1]] + lofs[k][1];
            stage[pos] = make_int2(pv[k].z, pv[k].w);
        }
    }
    __syncthreads();
    // ---- compact 4B write-back, paired into 8B NT stores (coalesced) ----
    {
        int nfull = len >> 1;
        for (int i = t; i < nfull; i += 1024) {
            int2 a = stage[2 * i];
            int2 b2 = stage[2 * i + 1];
            unsigned ua = (bf16rne(__int_as_float(a.y)) << 17) | (unsigned)(a.x & 0x1FFFF);
            unsigned ub = (bf16rne(__int_as_float(b2.y)) << 17) | (unsigned)(b2.x & 0x1FFFF);
            long long o = (long long)ua | ((long long)ub << 32);
            __builtin_nontemporal_store(o, (long long*)&ebuf4[s + 2 * i]);
        }
        if ((len & 1) && t == 0) {
            int2 a = stage[len - 1];
            ebuf4[s + len - 1] =
                (bf16rne(__int_as_float(a.y)) << 17) | (unsigned)(a.x & 0x1FFFF);
        }
    }
    // ---- degree -> dinv: 8 threads/node strided + shfl reduce ----
    {
        int n = t >> 3, l = t & 7;
        int st = base[n] - cnt[n], cn = cnt[n];
        float sum = 0.f;
        for (int i = l; i < cn; i += 8) sum += __int_as_float(stage[st + i].y);
        sum += __shfl_xor(sum, 1);
        sum += __shfl_xor(sum, 2);
        sum += __shfl_xor(sum, 4);
        if (l == 0) {
            float di = rsqrtf(sum + 1.0f);    // + self-loop
            sdinv[n] = di;
            int c = nbase + n;
            if (c < N_NODES) {
                rp[c] = make_int2(s + st, cn);
                dinv[c] = di;
            }
        }
    }
    __syncthreads();                          // stage reads done; xs overwrite ok

    // ---- fused xw1 for this bucket's 128 nodes ----
    for (int idx = t; idx < F_IN * H_DIM; idx += 1024) sW[idx] = W1[idx];
    int g0 = nbase * F_IN;
    int nfl = BUCKET_SZ * F_IN;               // 4736 floats
    for (int idx = t; idx < nfl; idx += 1024) {
        int gi = g0 + idx;
        xs[idx] = (gi < N_NODES * F_IN) ? __builtin_nontemporal_load(&x[gi]) : 0.f;
    }
    __syncthreads();
    // 8 threads/node, each computes 2 output cols {2*sub, 2*sub+1}
    {
        int n = t >> 3, sub = t & 7;
        int c = nbase + n;
        if (c < N_NODES) {
            const float* xi = &xs[n * F_IN];
            float a0 = 0.f, a1 = 0.f;
            for (int k = 0; k < F_IN; k++) {
                float xv = xi[k];
                a0 += xv * sW[k * H_DIM + 2 * sub];
                a1 += xv * sW[k * H_DIM + 2 * sub + 1];
            }
            float di = sdinv[n];
            unsigned pk = bf16rne(di * a0) | (bf16rne(di * a1) << 16);
            h1b[(size_t)c * 8 + sub] = pk;    // 32B/node, coalesced
        }
    }
}

// ---------- layer 1: 16 lanes/node (4 feature-quads x 4 segment-quarters),
//            8B gathers, shfl-combine, fused relu/bias + @W2 -> h2s ----------
__global__ __launch_bounds__(256) void k_agg1(
    const int2* __restrict__ rp, const unsigned* __restrict__ ebuf4,
    const uint2* __restrict__ h1b, const float* __restrict__ dinv,
    const float* __restrict__ b1, const float* __restrict__ W2,
    float* __restrict__ h2s)
{
    __shared__ float sW2[H_DIM * C_DIM];
    __shared__ float sb1[H_DIM];
    int t = threadIdx.x;
    if (t < H_DIM * C_DIM) sW2[t] = W2[t];
    if (t >= 32 && t < 32 + H_DIM) sb1[t - 32] = b1[t - 32];
    __syncthreads();
    int id = blockIdx.x * 256 + t;
    int c = id >> 4;                           // 16 lanes per node
    int sub = id & 15, q = sub & 3, h = sub >> 2;
    if (c >= N_NODES) return;
    int2 seg = rp[c];
    int s = seg.x, n = seg.y;
    int m = (n - h + 3) >> 2;                  // edges for this quarter (stride 4)
    int p0i = s + h;
    float4 acc = make_float4(0.f, 0.f, 0.f, 0.f);

#define PROC1(u)                                                    \
    {   float a = EW(u);                                            \
        uint2 g = h1b[(size_t)ER(u) * 4 + q];                       \
        acc.x += a * BLO(g.x); acc.y += a * BHI(g.x);               \
        acc.z += a * BLO(g.y); acc.w += a * BHI(g.y); }

    int k = 0;
    if (m >= 4) {
        unsigned e0 = __builtin_nontemporal_load(&ebuf4[p0i + 0]);
        unsigned e1 = __builtin_nontemporal_load(&ebuf4[p0i + 4]);
        unsigned e2 = __builtin_nontemporal_load(&ebuf4[p0i + 8]);
        unsigned e3 = __builtin_nontemporal_load(&ebuf4[p0i + 12]);
        for (; k + 8 <= m; k += 4) {
            unsigned f0 = __builtin_nontemporal_load(&ebuf4[p0i + 4 * (k + 4)]);
            unsigned f1 = __builtin_nontemporal_load(&ebuf4[p0i + 4 * (k + 5)]);
            unsigned f2 = __builtin_nontemporal_load(&ebuf4[p0i + 4 * (k + 6)]);
            unsigned f3 = __builtin_nontemporal_load(&ebuf4[p0i + 4 * (k + 7)]);
            PROC1(e0); PROC1(e1); PROC1(e2); PROC1(e3);
            e0 = f0; e1 = f1; e2 = f2; e3 = f3;
        }
        PROC1(e0); PROC1(e1); PROC1(e2); PROC1(e3);
        k += 4;
    }
    for (; k < m; k++) {
        unsigned u = __builtin_nontemporal_load(&ebuf4[p0i + 4 * k]);
        PROC1(u);
    }
#undef PROC1

    acc.x += __shfl_xor(acc.x, 4);  acc.x += __shfl_xor(acc.x, 8);
    acc.y += __shfl_xor(acc.y, 4);  acc.y += __shfl_xor(acc.y, 8);
    acc.z += __shfl_xor(acc.z, 4);  acc.z += __shfl_xor(acc.z, 8);
    acc.w += __shfl_xor(acc.w, 4);  acc.w += __shfl_xor(acc.w, 8);

    float dc = dinv[c];
    uint2 gc = h1b[(size_t)c * 4 + q];
    float hcv[4] = {BLO(gc.x), BHI(gc.x), BLO(gc.y), BHI(gc.y)};
    float av[4] = {acc.x + hcv[0], acc.y + hcv[1], acc.z + hcv[2], acc.w + hcv[3]};
    int j0 = q << 2;
    float p0 = 0.f, p1 = 0.f;
#pragma unroll
    for (int j = 0; j < 4; j++) {
        float rv = fmaxf(dc * av[j] + sb1[j0 + j], 0.f);
        p0 += rv * sW2[(j0 + j) * C_DIM + 0];
        p1 += rv * sW2[(j0 + j) * C_DIM + 1];
    }
    p0 += __shfl_xor(p0, 1); p0 += __shfl_xor(p0, 2);
    p1 += __shfl_xor(p1, 1); p1 += __shfl_xor(p1, 2);
    if (sub == 0) ((float2*)h2s)[c] = make_float2(dc * p0, dc * p1);
}

// ---------- layer 2: 8 lanes/node (segment eighths), shfl reduce,
//            + bias + log_softmax ----------
__global__ __launch_bounds__(256) void k_agg2(
    const int2* __restrict__ rp, const unsigned* __restrict__ ebuf4,
    const float* __restrict__ h2s, const float* __restrict__ dinv,
    const float* __restrict__ b2, float* __restrict__ out)
{
    int id = blockIdx.x * 256 + threadIdx.x;
    int c = id >> 3, sub = id & 7;
    if (c >= N_NODES) return;
    int2 seg = rp[c];
    int s = seg.x, n = seg.y;
    const float2* h22 = (const float2*)h2s;
    int m = (n - sub + 7) >> 3;                // edges for this eighth (stride 8)
    int p0i = s + sub;
    float a0 = 0.f, a1 = 0.f;

#define PROC2(u)                                                    \
    {   float a = EW(u);                                            \
        float2 hv = h22[ER(u)];                                     \
        a0 += a * hv.x;  a1 += a * hv.y; }

    int k = 0;
    if (m >= 4) {
        unsigned e0 = __builtin_nontemporal_load(&ebuf4[p0i + 0]);
        unsigned e1 = __builtin_nontemporal_load(&ebuf4[p0i + 8]);
        unsigned e2 = __builtin_nontemporal_load(&ebuf4[p0i + 16]);
        unsigned e3 = __builtin_nontemporal_load(&ebuf4[p0i + 24]);
        for (; k + 8 <= m; k += 4) {
            unsigned f0 = __builtin_nontemporal_load(&ebuf4[p0i + 8 * (k + 4)]);
            unsigned f1 = __builtin_nontemporal_load(&ebuf4[p0i + 8 * (k + 5)]);
            unsigned f2 = __builtin_nontemporal_load(&ebuf4[p0i + 8 * (k + 6)]);
            unsigned f3 = __builtin_nontemporal_load(&ebuf4[p0i + 8 * (k + 7)]);
            PROC2(e0); PROC2(e1); PROC2(e2); PROC2(e3);
            e0 = f0; e1 = f1; e2 = f2; e3 = f3;
        }
        PROC2(e0); PROC2(e1); PROC2(e2); PROC2(e3);
        k += 4;
    }
    for (; k < m; k++) {
        unsigned u = __builtin_nontemporal_load(&ebuf4[p0i + 8 * k]);
        PROC2(u);
    }
#undef PROC2

    a0 += __shfl_xor(a0, 1); a0 += __shfl_xor(a0, 2); a0 += __shfl_xor(a0, 4);
    a1 += __shfl_xor(a1, 1); a1 += __shfl_xor(a1, 2); a1 += __shfl_xor(a1, 4);
    if (sub == 0) {
        float dc = dinv[c];
        float2 hc = h22[c];
        float l0 = dc * (a0 + hc.x) + b2[0];
        float l1 = dc * (a1 + hc.y) + b2[1];
        float mx = fmaxf(l0, l1);
        float lse = mx + logf(expf(l0 - mx) + expf(l1 - mx));
        ((float2*)out)[c] = make_float2(l0 - lse, l1 - lse);
    }
}

extern "C" void kernel_launch(void* const* d_in, const int* in_sizes, int n_in,
                              void* d_out, int out_size, void* d_ws, size_t ws_size,
                              hipStream_t stream) {
    const float* x  = (const float*)d_in[0];
    const int*   ei = (const int*)d_in[1];     // [2, E]: row then col
    const float* w  = (const float*)d_in[2];
    const float* W1 = (const float*)d_in[3];
    const float* b1 = (const float*)d_in[4];
    const float* W2 = (const float*)d_in[5];
    const float* b2 = (const float*)d_in[6];
    float* out = (float*)d_out;

    const int* row = ei;
    const int* col = ei + N_EDGES;

    // workspace layout (64B-aligned offsets)
    char* ws = (char*)d_ws;
    int*      gcur  = (int*)(ws + 0);            //     3,200 B
    int2*     rp    = (int2*)(ws + 3200);        //   800,000 B
    float*    dinv  = (float*)(ws + 803200);     //   400,000 B
    unsigned* h1b   = (unsigned*)(ws + 1203200); // 3,200,000 B (bf16 16/row)
    float*    h2s   = (float*)(ws + 4403200);    //   800,000 B
    unsigned* ebuf4 = (unsigned*)(ws + 5203200); //14,814,208 B (782*4736*4)
    int2*     ebuf  = (int2*)(ws + 20017408);    //29,628,416 B (782*4736*8)
    // end: 49,645,824 B

    hipMemsetAsync(gcur, 0, 3200, stream);       // bucket counters = 0
    k_part    <<<NPBLK, 1024, 0, stream>>>(row, col, w, gcur, ebuf);
    k_sortxw1 <<<NBUCK, 1024, 0, stream>>>(gcur, ebuf, x, W1, ebuf4, rp, dinv, h1b);
    k_agg1    <<<(16 * N_NODES + 255) / 256, 256, 0, stream>>>(rp, ebuf4, (const uint2*)h1b, dinv, b1, W2, h2s);
    k_agg2    <<<(8 * N_NODES + 255) / 256, 256, 0, stream>>>(rp, ebuf4, h2s, dinv, b2, out);
}